// Round 1
// baseline (163.270 us; speedup 1.0000x reference)
//
#include <hip/hip_runtime.h>

// Fused: z = relu(conv3x3(relu(conv3x3(x,w1)+b1), w2)+b2)
// x: [16,512,512,3] f32 NHWC, w1: [3,3,3,4] HWIO, w2: [3,3,4,1]
// out: [16,508,508,1]

#define IH 512
#define IW 512
#define OH 508
#define OW 508
#define TH 32
#define TW 32

__global__ __launch_bounds__(256) void fused_conv_kernel(
    const float* __restrict__ x,
    const float* __restrict__ w1,
    const float* __restrict__ b1,
    const float* __restrict__ w2,
    const float* __restrict__ b2,
    float* __restrict__ out)
{
    // x tile with +4 halo: 36x36x3, row-major [row][col][ch]
    __shared__ float xs[36 * 36 * 3];                 // 15552 B
    // y tile: 34x34 points x 4 channels, [row][col][ch]
    __shared__ __align__(16) float ys[34 * 34 * 4];   // 18496 B
    __shared__ __align__(16) float ws1[112];          // 108 used
    __shared__ __align__(16) float ws2[36];
    __shared__ float wb[8];                           // b1[0..3], b2 at [4]

    const int tid = threadIdx.x;
    const int bb = blockIdx.z;
    const int h0 = blockIdx.y * TH;
    const int w0 = blockIdx.x * TW;

    // ---- load weights/biases into LDS (disjoint thread ranges) ----
    if (tid < 108) ws1[tid] = w1[tid];
    else if (tid >= 128 && tid < 164) ws2[tid - 128] = w2[tid - 128];
    else if (tid >= 192 && tid < 196) wb[tid - 192] = b1[tid - 192];
    else if (tid == 196) wb[4] = b2[0];

    // ---- stage x halo tile: 36 rows x (36 cols * 3 ch = 108 floats) ----
    const long xbase = (long)bb * IH * IW * 3;
    for (int i = tid; i < 36 * 108; i += 256) {
        int r = i / 108;
        int q = i - r * 108;      // col*3 + ci
        int cc = q / 3;
        int ci = q - cc * 3;
        int gh = h0 + r, gw = w0 + cc;
        float v = 0.f;
        if (gh < IH && gw < IW)
            v = x[xbase + ((long)gh * IW + gw) * 3 + ci];
        xs[i] = v;
    }
    __syncthreads();

    // ---- stage 1: conv1 + b1 + relu -> ys (34x34x4), 5 points/thread ----
    {
        float acc[5][4];
        int rr[5], cc[5];
#pragma unroll
        for (int k = 0; k < 5; ++k) {
            int p = tid + k * 256;
            if (p > 1155) p = 1155;         // clamp: duplicate compute, no write
            rr[k] = p / 34;
            cc[k] = p - rr[k] * 34;
            acc[k][0] = wb[0]; acc[k][1] = wb[1];
            acc[k][2] = wb[2]; acc[k][3] = wb[3];
        }
#pragma unroll
        for (int t = 0; t < 27; ++t) {      // t = (dr*3+dc)*3+ci
            const int dr = t / 9;
            const int dc = (t / 3) % 3;
            const int ci = t % 3;
            const float4 wv = *(const float4*)&ws1[t * 4];  // broadcast
#pragma unroll
            for (int k = 0; k < 5; ++k) {
                float xv = xs[(rr[k] + dr) * 108 + (cc[k] + dc) * 3 + ci];
                acc[k][0] = fmaf(xv, wv.x, acc[k][0]);
                acc[k][1] = fmaf(xv, wv.y, acc[k][1]);
                acc[k][2] = fmaf(xv, wv.z, acc[k][2]);
                acc[k][3] = fmaf(xv, wv.w, acc[k][3]);
            }
        }
#pragma unroll
        for (int k = 0; k < 5; ++k) {
            int p = tid + k * 256;
            if (p < 1156) {
                float4 v;
                v.x = fmaxf(acc[k][0], 0.f);
                v.y = fmaxf(acc[k][1], 0.f);
                v.z = fmaxf(acc[k][2], 0.f);
                v.w = fmaxf(acc[k][3], 0.f);
                *(float4*)&ys[p * 4] = v;
            }
        }
    }
    __syncthreads();

    // ---- stage 2: conv2 + b2 + relu -> out, 4 points/thread (32x32) ----
    {
        float zacc[4];
        int rr[4], cc[4];
#pragma unroll
        for (int k = 0; k < 4; ++k) {
            int p = tid + k * 256;
            rr[k] = p >> 5;
            cc[k] = p & 31;
            zacc[k] = wb[4];
        }
#pragma unroll
        for (int t = 0; t < 9; ++t) {       // t = dr*3+dc
            const int dr = t / 3;
            const int dc = t % 3;
            const float4 wv = *(const float4*)&ws2[t * 4];  // broadcast
#pragma unroll
            for (int k = 0; k < 4; ++k) {
                const float4 yv = *(const float4*)&ys[((rr[k] + dr) * 34 + cc[k] + dc) * 4];
                zacc[k] = fmaf(yv.x, wv.x, zacc[k]);
                zacc[k] = fmaf(yv.y, wv.y, zacc[k]);
                zacc[k] = fmaf(yv.z, wv.z, zacc[k]);
                zacc[k] = fmaf(yv.w, wv.w, zacc[k]);
            }
        }
        const long obase = (long)bb * OH * OW;
#pragma unroll
        for (int k = 0; k < 4; ++k) {
            int gh = h0 + rr[k], gw = w0 + cc[k];
            if (gh < OH && gw < OW)
                out[obase + (long)gh * OW + gw] = fmaxf(zacc[k], 0.f);
        }
    }
}

extern "C" void kernel_launch(void* const* d_in, const int* in_sizes, int n_in,
                              void* d_out, int out_size, void* d_ws, size_t ws_size,
                              hipStream_t stream) {
    const float* x  = (const float*)d_in[0];
    const float* w1 = (const float*)d_in[1];
    const float* b1 = (const float*)d_in[2];
    const float* w2 = (const float*)d_in[3];
    const float* b2 = (const float*)d_in[4];
    float* out = (float*)d_out;

    dim3 grid((OW + TW - 1) / TW, (OH + TH - 1) / TH, 16);  // (16,16,16)
    fused_conv_kernel<<<grid, dim3(256), 0, stream>>>(x, w1, b1, w2, b2, out);
}

// Round 2
// 127.595 us; speedup vs baseline: 1.2796x; 1.2796x over previous
//
#include <hip/hip_runtime.h>

// Fused: z = relu(conv3x3(relu(conv3x3(x,w1)+b1), w2)+b2)
// x: [16,512,512,3] f32 NHWC, w1: [3,3,3,4] HWIO, b1:[4], w2: [3,3,4,1], b2:[1]
// out: [16,508,508,1]
//
// Tile: 30x30 z-outputs per block; y tile 32x32 (x4ch), x tile 34x34 (x3ch).
// Key trick: NHWC with C=3 means one conv1 tap-row needs 9 CONSECUTIVE floats;
// y stored interleaved (C=4) means one conv2 tap-row needs 12 CONSECUTIVE floats.
// So all LDS reads are aligned float4 (b128). Weights read via uniform indices
// -> scalar s_loads (SGPR), never touching LDS or VALU addressing.

#define IH 512
#define IW 512
#define OH 508
#define OW 508
#define TZ 30          // z tile
#define XS 104         // xs row stride in floats (102 used + 2 pad)
#define YS 140         // ys row stride in floats (136 needed, 140 for bank spread)

__global__ __launch_bounds__(256, 4) void fused_conv_kernel(
    const float* __restrict__ x,
    const float* __restrict__ w1,
    const float* __restrict__ b1,
    const float* __restrict__ w2,
    const float* __restrict__ b2,
    float* __restrict__ out)
{
    __shared__ __align__(16) float xs[34 * XS];   // 14144 B
    __shared__ __align__(16) float ys[32 * YS];   // 17920 B

    const int tid = threadIdx.x;
    const int bb = blockIdx.z;
    const int h0 = blockIdx.y * TZ;
    const int w0 = blockIdx.x * TZ;

    // ---- stage x halo tile: 34 rows x 102 floats (34 cols * 3 ch) ----
    {
        const long xbase = (long)bb * IH * IW * 3;
        const int wf0 = w0 * 3;  // float offset of tile col 0 within a row
        for (int i = tid; i < 34 * 102; i += 256) {
            int r = i / 102;
            int q = i - r * 102;          // float offset within tile row
            int gh = h0 + r;
            int gwf = wf0 + q;            // float offset within global row
            float v = 0.f;
            if (gh < IH && gwf < IW * 3)
                v = x[xbase + (long)gh * (IW * 3) + gwf];
            xs[r * XS + q] = v;
        }
    }
    __syncthreads();

    // ---- stage 1: conv1 + b1 + relu -> ys (32 rows x 32 cols x 4 ch) ----
    // thread -> y row r = tid>>3, y cols 4j..4j+3 (j = tid&7). Exactly 256 tasks.
    {
        const int r = tid >> 3;
        const int j = tid & 7;
        float acc[4][4];
#pragma unroll
        for (int p = 0; p < 4; ++p)
#pragma unroll
            for (int oc = 0; oc < 4; ++oc)
                acc[p][oc] = b1[oc];                    // scalar (SGPR)

#pragma unroll
        for (int dr = 0; dr < 3; ++dr) {
            // 20-float window: x floats [12j .. 12j+19] of tile row r+dr
            const float4* src = (const float4*)&xs[(r + dr) * XS + 12 * j];
            float4 q0 = src[0], q1 = src[1], q2 = src[2], q3 = src[3], q4 = src[4];
            float win[20] = { q0.x,q0.y,q0.z,q0.w, q1.x,q1.y,q1.z,q1.w,
                              q2.x,q2.y,q2.z,q2.w, q3.x,q3.y,q3.z,q3.w,
                              q4.x,q4.y,q4.z,q4.w };
#pragma unroll
            for (int t = 0; t < 9; ++t) {               // t = dc*3 + ci
#pragma unroll
                for (int oc = 0; oc < 4; ++oc) {
                    const float wv = w1[(dr * 9 + t) * 4 + oc];   // uniform -> SGPR
#pragma unroll
                    for (int p = 0; p < 4; ++p)
                        acc[p][oc] = fmaf(win[3 * p + t], wv, acc[p][oc]);
                }
            }
        }
        // relu + store 16 consecutive floats: y[r][4j..4j+3][0..3]
        float4* dst = (float4*)&ys[r * YS + 16 * j];
#pragma unroll
        for (int p = 0; p < 4; ++p) {
            float4 v;
            v.x = fmaxf(acc[p][0], 0.f);
            v.y = fmaxf(acc[p][1], 0.f);
            v.z = fmaxf(acc[p][2], 0.f);
            v.w = fmaxf(acc[p][3], 0.f);
            dst[p] = v;
        }
    }
    __syncthreads();

    // ---- stage 2: conv2 + b2 + relu -> out. 240 tasks of 4 z-points ----
    if (tid < 240) {
        const int r = tid >> 3;          // z row 0..29
        const int k = tid & 7;           // col group: z cols 4k..4k+3
        float z[4];
        const float bias2 = b2[0];
#pragma unroll
        for (int p = 0; p < 4; ++p) z[p] = bias2;

#pragma unroll
        for (int dr = 0; dr < 3; ++dr) {
            // 24-float window: y floats [16k .. 16k+23] of y row r+dr
            const float4* src = (const float4*)&ys[(r + dr) * YS + 16 * k];
            float4 q0 = src[0], q1 = src[1], q2 = src[2],
                   q3 = src[3], q4 = src[4], q5 = src[5];
            float win[24] = { q0.x,q0.y,q0.z,q0.w, q1.x,q1.y,q1.z,q1.w,
                              q2.x,q2.y,q2.z,q2.w, q3.x,q3.y,q3.z,q3.w,
                              q4.x,q4.y,q4.z,q4.w, q5.x,q5.y,q5.z,q5.w };
#pragma unroll
            for (int t = 0; t < 12; ++t) {              // t = dc*4 + ciy
                const float wv = w2[dr * 12 + t];       // uniform -> SGPR
#pragma unroll
                for (int p = 0; p < 4; ++p)
                    z[p] = fmaf(win[4 * p + t], wv, z[p]);
            }
        }

        const long obase = (long)bb * OH * OW;
#pragma unroll
        for (int p = 0; p < 4; ++p) {
            int c = 4 * k + p;
            int gh = h0 + r, gw = w0 + c;
            if (c < TZ && gh < OH && gw < OW)
                out[obase + (long)gh * OW + gw] = fmaxf(z[p], 0.f);
        }
    }
}

extern "C" void kernel_launch(void* const* d_in, const int* in_sizes, int n_in,
                              void* d_out, int out_size, void* d_ws, size_t ws_size,
                              hipStream_t stream) {
    const float* x  = (const float*)d_in[0];
    const float* w1 = (const float*)d_in[1];
    const float* b1 = (const float*)d_in[2];
    const float* w2 = (const float*)d_in[3];
    const float* b2 = (const float*)d_in[4];
    float* out = (float*)d_out;

    dim3 grid((OW + TZ - 1) / TZ, (OH + TZ - 1) / TZ, 16);  // (17,17,16)
    fused_conv_kernel<<<grid, dim3(256), 0, stream>>>(x, w1, b1, w2, b2, out);
}